// Round 7
// baseline (206.148 us; speedup 1.0000x reference)
//
#include <hip/hip_runtime.h>

#define HID   1024
#define SLEN  2048
#define NHEAD 16
#define HDIM  64
#define SC2L  0.18033688f   // (1/sqrt(64)) * log2(e)

typedef unsigned short u16;
typedef _Float16 f16;
using bf16x8 = __attribute__((ext_vector_type(8))) short;
using h16x2  = __attribute__((ext_vector_type(2))) __fp16;
using h16x4  = __attribute__((ext_vector_type(4))) __fp16;
using f16x4  = __attribute__((ext_vector_type(4))) f16;
using f32x4  = __attribute__((ext_vector_type(4))) float;

typedef __attribute__((address_space(1))) void gvoid;
typedef __attribute__((address_space(3))) void lvoid;

__device__ __forceinline__ u16 f2bf(float f) {
  union { float f; unsigned u; } v; v.f = f;
  unsigned u = v.u;
  return (u16)((u + 0x7fffu + ((u >> 16) & 1u)) >> 16);
}

__device__ __forceinline__ void async_ld16(const u16* g, u16* l) {
  __builtin_amdgcn_global_load_lds((gvoid*)g, (lvoid*)l, 16, 0, 0);
}

// -------- prep: z<4 -> transpose+cast weight z; z==4 -> cast X fp32->bf16 --------
__global__ __launch_bounds__(256) void prep_kernel(const float* __restrict__ x,
                                                   const float* __restrict__ wq,
                                                   const float* __restrict__ wk,
                                                   const float* __restrict__ wv,
                                                   const float* __restrict__ wo,
                                                   u16* __restrict__ xb,
                                                   u16* __restrict__ wt) {
  const int tid = threadIdx.x;
  if (blockIdx.z == 4) {
    const int bid = blockIdx.y * 32 + blockIdx.x;
#pragma unroll
    for (int it = 0; it < 4; ++it) {
      const int i = bid * 1024 + it * 256 + tid;
      float4 v = ((const float4*)x)[i];
      ushort4 o;
      o.x = f2bf(v.x); o.y = f2bf(v.y); o.z = f2bf(v.z); o.w = f2bf(v.w);
      ((ushort4*)xb)[i] = o;
    }
    return;
  }
  const float* src = (blockIdx.z == 0) ? wq : (blockIdx.z == 1) ? wk
                   : (blockIdx.z == 2) ? wv : wo;
  u16* dst = wt + (size_t)blockIdx.z * (HID * HID);
  __shared__ float tile[32][33];
  const int n0 = blockIdx.x * 32, k0 = blockIdx.y * 32;
  const int xx = tid & 31, yy = tid >> 5;
  for (int i = yy; i < 32; i += 8)
    tile[i][xx] = src[(size_t)(k0 + i) * HID + n0 + xx];
  __syncthreads();
  for (int i = yy; i < 32; i += 8)
    dst[(size_t)(n0 + i) * HID + k0 + xx] = f2bf(tile[xx][i]);
}

// ------------- fused QKV GEMM -------------
// Q,K written row-major bf16. V written TRANSPOSED f16 to VT[b,h,d,s] via an
// LDS-transpose epilogue (xor-swizzled chunks), so flash needs no V conversion.
__global__ __launch_bounds__(256) void gemm_qkv_kernel(const u16* __restrict__ A,
                                                       const u16* __restrict__ Bt,
                                                       const float* __restrict__ bq,
                                                       const float* __restrict__ bk,
                                                       const float* __restrict__ bv,
                                                       u16* __restrict__ Qb,
                                                       u16* __restrict__ Kb,
                                                       u16* __restrict__ VTf) {
  __shared__ u16 smem[8192];                 // sA | sB, contiguous 16 KB
  u16* sA = smem;
  u16* sB = smem + 4096;
  const int tid  = threadIdx.x;
  const int wave = tid >> 6, lane = tid & 63;
  const int quad = lane >> 4, l16 = lane & 15;
  const int n0g = blockIdx.x * 128;
  const int region = blockIdx.x >> 3;        // 0=Q 1=K 2=V
  const int colbase = (blockIdx.x & 7) * 128;
  const int m0 = blockIdx.y * 128;
  const int wm = (wave & 1) * 64, wn = (wave >> 1) * 64;

  f32x4 acc[4][4] = {};
  const int srow = lane >> 2;
  const int scol = (lane & 3) * 8;

  for (int kt = 0; kt < HID; kt += 32) {
    __syncthreads();
    for (int c = wave; c < 8; c += 4) {
      async_ld16(A  + (size_t)(m0  + c * 16 + srow) * HID + kt + scol, &sA[c * 512]);
      async_ld16(Bt + (size_t)(n0g + c * 16 + srow) * HID + kt + scol, &sB[c * 512]);
    }
    __syncthreads();

    bf16x8 af[4], bfr[4];
#pragma unroll
    for (int t = 0; t < 4; ++t) {
      af[t]  = *(const bf16x8*)&sA[(wm + t * 16 + l16) * 32 + quad * 8];
      bfr[t] = *(const bf16x8*)&sB[(wn + t * 16 + l16) * 32 + quad * 8];
    }
#pragma unroll
    for (int mt = 0; mt < 4; ++mt)
#pragma unroll
      for (int nt = 0; nt < 4; ++nt)
        acc[mt][nt] = __builtin_amdgcn_mfma_f32_16x16x32_bf16(af[mt], bfr[nt],
                                                              acc[mt][nt], 0, 0, 0);
  }

  const float* bias = (region == 0) ? bq : (region == 1) ? bk : bv;
  float bvv[4];
#pragma unroll
  for (int nt = 0; nt < 4; ++nt) bvv[nt] = bias[colbase + wn + nt * 16 + l16];

  if (region == 2) {
    // --- transposed f16 epilogue: VT[(b*16+h)*64+d][s], two 64-col halves ---
    const int bb = m0 >> 11;            // batch
    const int m0loc = m0 & 2047;        // s offset within batch
    const int h0 = colbase >> 6;        // first head in this 128-col span
    u16* T = smem;                      // [64 d][128 s] u16, chunk-swizzled
#pragma unroll
    for (int h2 = 0; h2 < 2; ++h2) {
      __syncthreads();                  // prior readers of smem done
      if ((wave >> 1) == h2) {          // waves owning this 64-col half
#pragma unroll
        for (int mt = 0; mt < 4; ++mt)
#pragma unroll
          for (int nt = 0; nt < 4; ++nt)
#pragma unroll
            for (int r = 0; r < 4; ++r) {
              const int sl = (wave & 1) * 64 + mt * 16 + quad * 4 + r;  // 0..127
              const int dl = nt * 16 + l16;                             // 0..63
              union { f16 h; u16 u; } cv;
              cv.h = (f16)(acc[mt][nt][r] + bvv[nt]);
              T[dl * 128 + (((sl >> 3) ^ l16) * 8) + (sl & 7)] = cv.u;
            }
      }
      __syncthreads();
      const int d = tid >> 2, sg = (tid & 3) * 4;
      u16* drow = VTf + (size_t)((bb * NHEAD + h0 + h2) * HDIM + d) * SLEN + m0loc;
#pragma unroll
      for (int cc = 0; cc < 4; ++cc) {
        const int cl = sg + cc;
        const int ph = cl ^ (d & 15);
        *(bf16x8*)(drow + cl * 8) = *(const bf16x8*)&T[d * 128 + ph * 8];
      }
    }
    return;
  }

  u16* C = (region == 0) ? Qb : Kb;
#pragma unroll
  for (int mt = 0; mt < 4; ++mt)
#pragma unroll
    for (int r = 0; r < 4; ++r) {
      const int row = m0 + wm + mt * 16 + quad * 4 + r;
#pragma unroll
      for (int nt = 0; nt < 4; ++nt) {
        const int col = colbase + wn + nt * 16 + l16;
        C[(size_t)row * HID + col] = f2bf(acc[mt][nt][r] + bvv[nt]);
      }
    }
}

// ------------- O-proj GEMM: out[4096][1024] = A @ Wt^T + b (fp32 out) -------------
__global__ __launch_bounds__(256) void gemm_o_kernel(const u16* __restrict__ A,
                                                     const u16* __restrict__ Bt,
                                                     const float* __restrict__ bias,
                                                     float* __restrict__ Cf) {
  __shared__ u16 sA[64 * 32];
  __shared__ u16 sB[128 * 32];
  const int tid  = threadIdx.x;
  const int wave = tid >> 6, lane = tid & 63;
  const int quad = lane >> 4, l16 = lane & 15;
  const int n0 = blockIdx.x * 128;
  const int m0 = blockIdx.y * 64;
  const int wn = wave * 32;

  f32x4 acc[4][2] = {};
  const int srow = lane >> 2;
  const int scol = (lane & 3) * 8;

  for (int kt = 0; kt < HID; kt += 32) {
    __syncthreads();
    for (int c = wave; c < 12; c += 4) {
      if (c < 4) async_ld16(A  + (size_t)(m0 + c * 16 + srow) * HID + kt + scol, &sA[c * 512]);
      else       async_ld16(Bt + (size_t)(n0 + (c - 4) * 16 + srow) * HID + kt + scol,
                            &sB[(c - 4) * 512]);
    }
    __syncthreads();

    bf16x8 af[4], bfr[2];
#pragma unroll
    for (int t = 0; t < 4; ++t)
      af[t] = *(const bf16x8*)&sA[(t * 16 + l16) * 32 + quad * 8];
#pragma unroll
    for (int t = 0; t < 2; ++t)
      bfr[t] = *(const bf16x8*)&sB[(wn + t * 16 + l16) * 32 + quad * 8];
#pragma unroll
    for (int mt = 0; mt < 4; ++mt)
#pragma unroll
      for (int nt = 0; nt < 2; ++nt)
        acc[mt][nt] = __builtin_amdgcn_mfma_f32_16x16x32_bf16(af[mt], bfr[nt],
                                                              acc[mt][nt], 0, 0, 0);
  }

  float bvv[2];
#pragma unroll
  for (int nt = 0; nt < 2; ++nt) bvv[nt] = bias[n0 + wn + nt * 16 + l16];
#pragma unroll
  for (int mt = 0; mt < 4; ++mt)
#pragma unroll
    for (int r = 0; r < 4; ++r) {
      const int row = m0 + mt * 16 + quad * 4 + r;
#pragma unroll
      for (int nt = 0; nt < 2; ++nt)
        Cf[(size_t)row * HID + n0 + wn + nt * 16 + l16] = acc[mt][nt][r] + bvv[nt];
    }
}

// ---------------- causal flash attention, v6 ----------------
// 128-row K-tiles: each wave owns TWO 16-row k-strips (2x ILP per barrier window),
// 17 iterations per block EXACTLY (ceil((xb+1)/2)+ceil((32-xb)/2)==17 for all xb).
// Async swizzled staging, dbuf, 1 barrier/iter. K bf16 [k][d]; V^T f16 [d][k].
__global__ __launch_bounds__(256, 2) void flash_attn_kernel(const u16* __restrict__ Q,
                                                            const u16* __restrict__ K,
                                                            const u16* __restrict__ VT,
                                                            const int* __restrict__ mask,
                                                            u16* __restrict__ O) {
  const int xb = blockIdx.x, h = blockIdx.y, b = blockIdx.z;
  const int tid  = threadIdx.x;
  const int wave = tid >> 6, lane = tid & 63;
  const int quad = lane >> 4, l16 = lane & 15;

  __shared__ alignas(16) char smraw[66560];
  u16*   Ks = (u16*)smraw;                   // [2][128 k][64 d] bf16, chunk-swizzled
  u16*   Vt = (u16*)(smraw + 32768);         // [2][64 d][128 k] f16, chunk-swizzled
  float* lb = (float*)(smraw + 65536);       // [4][64]
  float* Ob0 = (float*)smraw;                // [64][66] f32 (epilogue alias)
  float* Ob1 = (float*)(smraw + 16896);

  const u16* Kh  = K  + (size_t)b * SLEN * HID + h * HDIM;
  const u16* Vth = VT + (size_t)((b * NHEAD + h) * HDIM) * SLEN;

  // K staging: async a covers k-rows wave*32+a*8 .. +7; lane -> (row kr8, chunk kc)
  const int kr8 = lane >> 3, kc = lane & 7;
  const int kgch = kc ^ (kr8 & 7);           // global chunk (xor-swizzled store)
  // V staging: async a covers d-rows wave*16+a*4 .. +3; lane -> (d vdl, chunk vc)
  const int vdl = lane >> 4, vc = lane & 15;

  for (int phase = 0; phase < 2; ++phase) {
    const int qt = phase ? (31 - xb) : xb;
    const int q0 = qt * 64;
    const int jn = (qt >> 1) + 1;            // # of 128-row K-tiles

    // Q B-frags once per phase: B[d=quad*8+e (+32)][q=nt*16+l16]
    bf16x8 qb[4][2];
#pragma unroll
    for (int nt = 0; nt < 4; ++nt) {
      const u16* qp = Q + (size_t)(b * SLEN + q0 + nt * 16 + l16) * HID + h * HDIM + quad * 8;
      qb[nt][0] = *(const bf16x8*)qp;
      qb[nt][1] = *(const bf16x8*)(qp + 32);
    }

    f32x4 oacc[4][4] = {};                   // k-partial O^T [dt][nt]
    float l_part[4] = {0.f, 0.f, 0.f, 0.f};

    // stage tile j=0 into buf 0 (8 asyncs/wave)
#pragma unroll
    for (int a = 0; a < 4; ++a) {
      async_ld16(Kh + (size_t)(wave * 32 + a * 8 + kr8) * HID + kgch * 8,
                 Ks + (wave * 32 + a * 8) * 64);
      const int d = wave * 16 + a * 4 + vdl;
      async_ld16(Vth + (size_t)d * SLEN + (vc ^ (d & 15)) * 8,
                 Vt + (wave * 16 + a * 4) * 128);
    }
    __syncthreads();   // drains vmcnt -> tile 0 ready (also fences prev phase LDS)

    for (int j = 0; j < jn; ++j) {
      const int buf = j & 1;
      u16* KsB = Ks + buf * 8192;
      u16* VtB = Vt + buf * 8192;

      if (j + 1 < jn) {    // prefetch j+1 into other buffer during compute
        u16* Kd = Ks + (buf ^ 1) * 8192;
        u16* Vd = Vt + (buf ^ 1) * 8192;
        const int kb = (j + 1) * 128;
#pragma unroll
        for (int a = 0; a < 4; ++a) {
          async_ld16(Kh + (size_t)(kb + wave * 32 + a * 8 + kr8) * HID + kgch * 8,
                     Kd + (wave * 32 + a * 8) * 64);
          const int d = wave * 16 + a * 4 + vdl;
          async_ld16(Vth + (size_t)d * SLEN + kb + (vc ^ (d & 15)) * 8,
                     Vd + (wave * 16 + a * 4) * 128);
        }
      }

      // ---- S^T: two independent 16-row k-strips per wave ----
      float p[2][4][4];
#pragma unroll
      for (int sub = 0; sub < 2; ++sub) {
        const int krow = wave * 32 + sub * 16 + l16;
        const u16* kp = KsB + krow * 64;
        const int ph0 = quad ^ (l16 & 7);
        const bf16x8 ka0 = *(const bf16x8*)(kp + ph0 * 8);
        const bf16x8 ka1 = *(const bf16x8*)(kp + (ph0 ^ 4) * 8);
        const int4 mi = *(const int4*)(mask + b * SLEN + j * 128 + wave * 32 + sub * 16 + quad * 4);
        float map[4];
        map[0] = mi.x ? 0.f : -1e30f;  map[1] = mi.y ? 0.f : -1e30f;
        map[2] = mi.z ? 0.f : -1e30f;  map[3] = mi.w ? 0.f : -1e30f;
#pragma unroll
        for (int nt = 0; nt < 4; ++nt) {
          f32x4 z = {0.f, 0.f, 0.f, 0.f};
          z = __builtin_amdgcn_mfma_f32_16x16x32_bf16(ka0, qb[nt][0], z, 0, 0, 0);
          z = __builtin_amdgcn_mfma_f32_16x16x32_bf16(ka1, qb[nt][1], z, 0, 0, 0);
#pragma unroll
          for (int r = 0; r < 4; ++r)
            p[sub][nt][r] = exp2f(fmaf(z[r], SC2L, map[r]));
        }
      }
      if (j == jn - 1) {   // causal + overhang zeroing (block-uniform branch)
#pragma unroll
        for (int sub = 0; sub < 2; ++sub)
#pragma unroll
          for (int nt = 0; nt < 4; ++nt)
#pragma unroll
            for (int r = 0; r < 4; ++r) {
              const int kg = j * 128 + wave * 32 + sub * 16 + quad * 4 + r;
              if (kg > q0 + nt * 16 + l16) p[sub][nt][r] = 0.f;
            }
      }

      f16x4 pb[2][4];
#pragma unroll
      for (int sub = 0; sub < 2; ++sub)
#pragma unroll
        for (int nt = 0; nt < 4; ++nt) {
          l_part[nt] += (p[sub][nt][0] + p[sub][nt][1]) + (p[sub][nt][2] + p[sub][nt][3]);
          const h16x2 lo = __builtin_amdgcn_cvt_pkrtz(p[sub][nt][0], p[sub][nt][1]);
          const h16x2 hi = __builtin_amdgcn_cvt_pkrtz(p[sub][nt][2], p[sub][nt][3]);
          const h16x4 packed = __builtin_shufflevector(lo, hi, 0, 1, 2, 3);
          pb[sub][nt] = __builtin_bit_cast(f16x4, packed);
        }

      // ---- PV: O^T[d][q] += V^T(strip) . P^T(strip), both subs ----
#pragma unroll
      for (int dt = 0; dt < 4; ++dt) {
        const int d = dt * 16 + l16;
#pragma unroll
        for (int sub = 0; sub < 2; ++sub) {
          const int ph = (wave * 4 + sub * 2 + (quad >> 1)) ^ l16;
          const f16x4 va = *(const f16x4*)(VtB + d * 128 + ph * 8 + (quad & 1) * 4);
#pragma unroll
          for (int nt = 0; nt < 4; ++nt)
            oacc[dt][nt] = __builtin_amdgcn_mfma_f32_16x16x16f16(va, pb[sub][nt],
                                                                 oacc[dt][nt], 0, 0, 0);
        }
      }
      __syncthreads();  // buf readers done + prefetch drained
    }

    // ---- epilogue: reduce l over quads; reduce partial O^T across wave pairs ----
#pragma unroll
    for (int nt = 0; nt < 4; ++nt) {
      l_part[nt] += __shfl_xor(l_part[nt], 16);
      l_part[nt] += __shfl_xor(l_part[nt], 32);
    }
    if (quad == 0)
#pragma unroll
      for (int nt = 0; nt < 4; ++nt) lb[wave * 64 + nt * 16 + l16] = l_part[nt];

    if ((wave & 1) == 0) {
      float* ob = (wave == 0) ? Ob0 : Ob1;
#pragma unroll
      for (int dt = 0; dt < 4; ++dt)
#pragma unroll
        for (int nt = 0; nt < 4; ++nt)
#pragma unroll
          for (int r = 0; r < 4; ++r)
            ob[(dt * 16 + quad * 4 + r) * 66 + nt * 16 + l16] = oacc[dt][nt][r];
    }
    __syncthreads();
    if (wave & 1) {
      float* ob = (wave == 1) ? Ob0 : Ob1;
#pragma unroll
      for (int dt = 0; dt < 4; ++dt)
#pragma unroll
        for (int nt = 0; nt < 4; ++nt)
#pragma unroll
          for (int r = 0; r < 4; ++r)
            ob[(dt * 16 + quad * 4 + r) * 66 + nt * 16 + l16] += oacc[dt][nt][r];
    }
    __syncthreads();

    {  // final: thread t -> q = t>>2, 16-d chunk = t&3; normalize + bf16 store
      const int q  = tid >> 2;
      const int dc = tid & 3;
      const float l = lb[q] + lb[64 + q] + lb[128 + q] + lb[192 + q];
      const float inv = 1.f / l;
      u16 ob[16];
#pragma unroll
      for (int e = 0; e < 16; ++e) {
        const int d = dc * 16 + e;
        ob[e] = f2bf((Ob0[d * 66 + q] + Ob1[d * 66 + q]) * inv);
      }
      u16* op = O + (size_t)(b * SLEN + q0 + q) * HID + h * HDIM + dc * 16;
      *(bf16x8*)op       = *(bf16x8*)&ob[0];
      *(bf16x8*)(op + 8) = *(bf16x8*)&ob[8];
    }
    __syncthreads();   // epilogue LDS reads done before next phase restages
  }
}

// ---------------- launcher ----------------
extern "C" void kernel_launch(void* const* d_in, const int* in_sizes, int n_in,
                              void* d_out, int out_size, void* d_ws, size_t ws_size,
                              hipStream_t stream) {
  const float* x    = (const float*)d_in[0];
  const int*   mask = (const int*)d_in[1];
  const float* wq   = (const float*)d_in[2];
  const float* bq   = (const float*)d_in[3];
  const float* wk   = (const float*)d_in[4];
  const float* bk   = (const float*)d_in[5];
  const float* wv   = (const float*)d_in[6];
  const float* bv   = (const float*)d_in[7];
  const float* wo   = (const float*)d_in[8];
  const float* bo   = (const float*)d_in[9];
  float* out = (float*)d_out;

  char* ws = (char*)d_ws;
  u16* XBF = (u16*)(ws);                      // 8 MB (dead after QKV GEMM)
  u16* WT  = (u16*)(ws + (8u  << 20));        // 4x2 MB transposed bf16 weights
  u16* QBF = (u16*)(ws + (16u << 20));        // 8 MB
  u16* KBF = (u16*)(ws + (24u << 20));        // 8 MB
  u16* VTF = (u16*)(ws + (32u << 20));        // 8 MB f16 V^T [b,h,d,s]
  u16* ATT = (u16*)(ws);                      // 8 MB, reuses XBF slot

  prep_kernel<<<dim3(32, 32, 5), 256, 0, stream>>>(x, wq, wk, wv, wo, XBF, WT);
  gemm_qkv_kernel<<<dim3(24, 32), 256, 0, stream>>>(XBF, WT, bq, bk, bv, QBF, KBF, VTF);
  flash_attn_kernel<<<dim3(16, NHEAD, 2), 256, 0, stream>>>(QBF, KBF, VTF, mask, ATT);
  gemm_o_kernel<<<dim3(8, 64), 256, 0, stream>>>(ATT, WT + (3u << 20), bo, out);
}